// Round 2
// baseline (552.354 us; speedup 1.0000x reference)
//
#include <hip/hip_runtime.h>
#include <hip/hip_bf16.h>
#include <math.h>

#define NN 20000
#define NE 320000
#define IN_F 16
#define OUT_F 16
#define EHID 64
#define BN_EPS 1e-5f
#define MAXC 8

// -------------------- edge path: one LANE per edge --------------------
// msg[e,o] = sum_i x[i] * ( be2[i*16+o] + sum_h eh[h]*We2[h*256+i*16+o] )
// eh[h] = relu(be1[h] + sum_i ef[i]*We1[i*64+h])
// Weight indices wave-uniform -> s_load/SGPR operands (no vector load cost).
// launch_bounds(256,2): VGPR budget 256/wave so ef/x/msg (48 f32) stay in regs.
__global__ __launch_bounds__(256, 2) void edge_kernel(
    const float* __restrict__ h_neigh, const float* __restrict__ efeat,
    const int* __restrict__ src, const int* __restrict__ dst,
    const float* __restrict__ We1, const float* __restrict__ be1,
    const float* __restrict__ We2, const float* __restrict__ be2,
    float* __restrict__ neigh, int cmask)
{
    int e = blockIdx.x * 256 + threadIdx.x;
    if (e >= NE) return;
    int s = src[e];
    int d = dst[e];

    float ef[16], x[16], msg[16];
    const float4* e4 = (const float4*)(efeat + (size_t)e * 16);
    const float4* x4 = (const float4*)(h_neigh + (size_t)s * 16);
#pragma unroll
    for (int k = 0; k < 4; k++) {
        float4 a = e4[k];
        ef[4*k+0] = a.x; ef[4*k+1] = a.y; ef[4*k+2] = a.z; ef[4*k+3] = a.w;
        float4 b = x4[k];
        x[4*k+0] = b.x; x[4*k+1] = b.y; x[4*k+2] = b.z; x[4*k+3] = b.w;
    }

#pragma unroll
    for (int o = 0; o < 16; o++) msg[o] = 0.f;

    // be2 contribution: msg += x @ be2[16x16]
#pragma unroll
    for (int i = 0; i < 16; i++) {
        float xi = x[i];
#pragma unroll
        for (int o = 0; o < 16; o++) msg[o] += xi * be2[i*16 + o];
    }

    for (int h = 0; h < EHID; h++) {
        float acc = be1[h];
#pragma unroll
        for (int i = 0; i < 16; i++) acc += ef[i] * We1[i*64 + h];
        acc = fmaxf(acc, 0.f);
        const float* w = We2 + (size_t)h * 256;
#pragma unroll
        for (int i = 0; i < 16; i++) {
            float exi = acc * x[i];
#pragma unroll
            for (int o = 0; o < 16; o++) msg[o] += exi * w[i*16 + o];
        }
    }

    // XCD-local copy: blocks round-robin across XCDs, so blockIdx&7 keeps
    // the atomic's line in this XCD's L2 (no cross-XCD ping-pong).
    float* np = neigh + ((size_t)(blockIdx.x & cmask) * NN + d) * 16;
#pragma unroll
    for (int o = 0; o < 16; o++) atomicAdd(np + o, msg[o]);
}

// -------------------- self path: y = h_self @ W, BN stats --------------------
__global__ __launch_bounds__(256) void self_stats_kernel(
    const float* __restrict__ h_self, const float* __restrict__ W,
    float* __restrict__ y, float* __restrict__ bnacc)
{
    int n = blockIdx.x * 256 + threadIdx.x;
    bool act = (n < NN);
    float hv[16], yv[16];
    if (act) {
        const float4* h4 = (const float4*)(h_self + (size_t)n * 16);
#pragma unroll
        for (int k = 0; k < 4; k++) {
            float4 a = h4[k];
            hv[4*k+0] = a.x; hv[4*k+1] = a.y; hv[4*k+2] = a.z; hv[4*k+3] = a.w;
        }
    } else {
#pragma unroll
        for (int i = 0; i < 16; i++) hv[i] = 0.f;
    }
#pragma unroll
    for (int o = 0; o < 16; o++) {
        float a = 0.f;
#pragma unroll
        for (int i = 0; i < 16; i++) a += hv[i] * W[i*16 + o];
        yv[o] = a;
    }
    if (act) {
        float4* y4 = (float4*)(y + (size_t)n * 16);
#pragma unroll
        for (int k = 0; k < 4; k++)
            y4[k] = make_float4(yv[4*k+0], yv[4*k+1], yv[4*k+2], yv[4*k+3]);
    }
    int lane = threadIdx.x & 63;
#pragma unroll
    for (int o = 0; o < 16; o++) {
        float a = act ? yv[o] : 0.f;
        float b = act ? yv[o]*yv[o] : 0.f;
#pragma unroll
        for (int off = 32; off > 0; off >>= 1) {
            a += __shfl_down(a, off);
            b += __shfl_down(b, off);
        }
        if (lane == 0) {
            atomicAdd(&bnacc[o], a);
            atomicAdd(&bnacc[16 + o], b);
        }
    }
}

// ------ finalize: sum neigh copies + BN + tanh + add + relu + L2-normalize ------
__global__ __launch_bounds__(256) void final_kernel(
    const float* __restrict__ y, const float* __restrict__ neigh, int ncopies,
    const float* __restrict__ bnacc, const float* __restrict__ gamma,
    const float* __restrict__ beta, float* __restrict__ out)
{
    int n = blockIdx.x * 256 + threadIdx.x;
    if (n >= NN) return;
    float nv[16];
#pragma unroll
    for (int o = 0; o < 16; o++) nv[o] = 0.f;
    for (int c = 0; c < ncopies; c++) {
        const float4* p4 = (const float4*)(neigh + ((size_t)c * NN + n) * 16);
#pragma unroll
        for (int k = 0; k < 4; k++) {
            float4 a = p4[k];
            nv[4*k+0] += a.x; nv[4*k+1] += a.y; nv[4*k+2] += a.z; nv[4*k+3] += a.w;
        }
    }
    float z[16];
    float ss = 0.f;
    const float inv_n = 1.f / (float)NN;
#pragma unroll
    for (int o = 0; o < 16; o++) {
        float mu  = bnacc[o] * inv_n;
        float var = bnacc[16 + o] * inv_n - mu * mu;
        float inv = rsqrtf(var + BN_EPS);
        float yv  = (y[(size_t)n*16 + o] - mu) * inv * gamma[o] + beta[o];
        float t   = tanhf(yv);
        float zz  = fmaxf(t + nv[o], 0.f);
        z[o] = zz;
        ss += zz * zz;
    }
    float nrm = sqrtf(ss);
    if (nrm == 0.f) nrm = 1.f;
    float r = 1.f / nrm;
#pragma unroll
    for (int o = 0; o < 16; o++) out[(size_t)n*16 + o] = z[o] * r;
}

extern "C" void kernel_launch(void* const* d_in, const int* in_sizes, int n_in,
                              void* d_out, int out_size, void* d_ws, size_t ws_size,
                              hipStream_t stream) {
    const float* h_neigh = (const float*)d_in[0];
    const float* h_self  = (const float*)d_in[1];
    const float* efeat   = (const float*)d_in[2];
    const int*   src     = (const int*)d_in[3];
    const int*   dst     = (const int*)d_in[4];
    const float* W_self  = (const float*)d_in[5];
    const float* gamma   = (const float*)d_in[6];
    const float* beta    = (const float*)d_in[7];
    const float* We1     = (const float*)d_in[8];
    const float* be1     = (const float*)d_in[9];
    const float* We2     = (const float*)d_in[10];
    const float* be2     = (const float*)d_in[11];
    float* out = (float*)d_out;

    const size_t neigh_bytes = (size_t)NN * 16 * 4;   // per copy
    const size_t y_bytes     = (size_t)NN * 16 * 4;
    // choose copy count by available ws
    int ncopies = 1;
    if (ws_size >= (size_t)MAXC * neigh_bytes + 128 + y_bytes) ncopies = MAXC;
    int cmask = ncopies - 1;

    char* ws = (char*)d_ws;
    float* neigh = (float*)ws;
    float* bnacc = (float*)(ws + (size_t)ncopies * neigh_bytes);
    float* y     = (float*)(ws + (size_t)ncopies * neigh_bytes + 128);

    // zero neigh copies + BN accumulators (ws is poisoned 0xAA each call)
    hipMemsetAsync(d_ws, 0, (size_t)ncopies * neigh_bytes + 128, stream);

    edge_kernel<<<(NE + 255)/256, 256, 0, stream>>>(
        h_neigh, efeat, src, dst, We1, be1, We2, be2, neigh, cmask);
    self_stats_kernel<<<(NN + 255)/256, 256, 0, stream>>>(h_self, W_self, y, bnacc);
    final_kernel<<<(NN + 255)/256, 256, 0, stream>>>(y, neigh, ncopies, bnacc, gamma, beta, out);
}

// Round 4
// 264.306 us; speedup vs baseline: 2.0898x; 2.0898x over previous
//
#include <hip/hip_runtime.h>
#include <hip/hip_bf16.h>
#include <math.h>

#define NN 20000
#define NE 320000
#define BN_EPS 1e-5f

// ws layout
#define NEIGH_BYTES (NN * 16 * 4)
#define BNACC_OFF   NEIGH_BYTES
#define Y_OFF       (NEIGH_BYTES + 128)

typedef __bf16 bf16x8 __attribute__((ext_vector_type(8)));
typedef float  f32x4  __attribute__((ext_vector_type(4)));

union BF8 { bf16x8 v; unsigned short us[8]; };

__device__ __forceinline__ unsigned short f2bf(float f) {
    unsigned int u = __builtin_bit_cast(unsigned int, f);
    u += 0x7FFFu + ((u >> 16) & 1u);   // RNE
    return (unsigned short)(u >> 16);
}
__device__ __forceinline__ float bf2f(unsigned short s) {
    unsigned int u = ((unsigned int)s) << 16;
    return __builtin_bit_cast(float, u);
}

// ============================ edge path ============================
// Per wave: 16 edges. eh = relu(ef@We1+be1) via hi/lo-split MFMA (fp32-class
// precision). eh stored to LDS as hi+lo bf16 planes in B-fragment order.
// Stage 3: edge_w^T = We2^T[256,64] @ eh^T with A=We2 single bf16,
// B=eh hi+lo (4 MFMA per mb), x-reduction fused in fp32.
// Lane ends holding msg[edge=L&15][o=(L>>4)*4+r] -> 4 atomicAdds.
__global__ __launch_bounds__(256) void edge_kernel(
    const float* __restrict__ h_neigh, const float* __restrict__ efeat,
    const int* __restrict__ src, const int* __restrict__ dst,
    const float* __restrict__ We1, const float* __restrict__ be1,
    const float* __restrict__ We2, const float* __restrict__ be2,
    float* __restrict__ neigh)
{
    // B-frag We1 hi/lo (K padded 16->32): [part][nb2][lane][j]  8 KB
    __shared__ __align__(16) unsigned short We1sw[2][4 * 64 * 8];
    // A-frag We2^T: [mb][kb][lane][j]  32 KB
    __shared__ __align__(16) unsigned short A3sw[16 * 2 * 64 * 8];
    // per-wave eh^T hi/lo in B-frag order: [part][wave][1024]  16 KB
    __shared__ __align__(16) unsigned short ehTsw[2][4][1024];

    const int t = threadIdx.x;

    // ---- init We1sw: lane holds B[(L>>4)*8+j][nb2*16+(L&15)], hi+lo parts
    {
        int nb2 = t >> 6, Li = t & 63, qq = Li >> 4, lo = Li & 15;
        BF8 vh, vl;
#pragma unroll
        for (int j = 0; j < 8; j++) {
            if (qq < 2) {
                float w  = We1[(qq * 8 + j) * 64 + nb2 * 16 + lo];
                unsigned short h = f2bf(w);
                vh.us[j] = h;
                vl.us[j] = f2bf(w - bf2f(h));
            } else { vh.us[j] = 0; vl.us[j] = 0; }
        }
        *(bf16x8*)&We1sw[0][t * 8] = vh.v;
        *(bf16x8*)&We1sw[1][t * 8] = vl.v;
    }
    // ---- init A3sw from We2 (coalesced float4 reads, swizzled b16 writes)
    {
        const float4* W2v = (const float4*)We2;
#pragma unroll
        for (int it = 0; it < 16; it++) {
            int c4 = t + 256 * it;          // 0..4095 float4 chunks
            float4 w = W2v[c4];
            int f = c4 * 4;
            int h = f >> 8, c = f & 255;
            int mb = c >> 4, kb = h >> 5, hh = h & 31, co = c & 15;
            int base = ((mb * 2 + kb) * 64 + (hh >> 3) * 16) * 8 + (hh & 7);
            A3sw[base + (co + 0) * 8] = f2bf(w.x);
            A3sw[base + (co + 1) * 8] = f2bf(w.y);
            A3sw[base + (co + 2) * 8] = f2bf(w.z);
            A3sw[base + (co + 3) * 8] = f2bf(w.w);
        }
    }
    __syncthreads();

    const int L = t & 63, wv = t >> 6;
    const int lo16 = L & 15, q = L >> 4;
    const int qc = q & 1;   // clamped chunk index (keeps q>=2 loads in-bounds)

    float be1v[4];
#pragma unroll
    for (int nb2 = 0; nb2 < 4; nb2++) be1v[nb2] = be1[nb2 * 16 + lo16];

    // A-frag of be2^T: lane holds be2[(q*8+j)*16 + lo16], zero for q>=2
    BF8 be2T;
#pragma unroll
    for (int j = 0; j < 8; j++) {
        float bv = be2[(qc * 8 + j) * 16 + lo16];
        be2T.us[j] = (q < 2) ? f2bf(bv) : (unsigned short)0;
    }
    unsigned short* ehTH = &ehTsw[0][wv][0];
    unsigned short* ehTL = &ehTsw[1][wv][0];

    for (int bt = blockIdx.x; bt < NE / 64; bt += gridDim.x) {
        int e = bt * 64 + wv * 16 + lo16;   // this lane's edge
        int se = src[e];
        int de = dst[e];

        // x row (kept fp32 for the fused reduction)
        float xr[16];
        {
            const float4* xp = (const float4*)(h_neigh + (size_t)se * 16);
#pragma unroll
            for (int k4 = 0; k4 < 4; k4++) {
                float4 a = xp[k4];
                xr[k4*4+0] = a.x; xr[k4*4+1] = a.y; xr[k4*4+2] = a.z; xr[k4*4+3] = a.w;
            }
        }

        // A2 frags hi/lo: ef[edge=lo16][k=q*8+j], zero-padded for q>=2
        BF8 a2h, a2l;
        {
            const float4* ep = (const float4*)(efeat + (size_t)e * 16 + qc * 8);
            float4 e0 = ep[0], e1 = ep[1];
            float ev[8] = {e0.x, e0.y, e0.z, e0.w, e1.x, e1.y, e1.z, e1.w};
#pragma unroll
            for (int j = 0; j < 8; j++) {
                if (q < 2) {
                    unsigned short h = f2bf(ev[j]);
                    a2h.us[j] = h;
                    a2l.us[j] = f2bf(ev[j] - bf2f(h));
                } else { a2h.us[j] = 0; a2l.us[j] = 0; }
            }
        }

        // stage 2: eh = relu(ef@We1+be1), hi/lo emulation (drop lo*lo term)
#pragma unroll
        for (int nb2 = 0; nb2 < 4; nb2++) {
            bf16x8 b1h = *(const bf16x8*)&We1sw[0][(nb2 * 64 + L) * 8];
            bf16x8 b1l = *(const bf16x8*)&We1sw[1][(nb2 * 64 + L) * 8];
            f32x4 c2 = {0.f, 0.f, 0.f, 0.f};
            c2 = __builtin_amdgcn_mfma_f32_16x16x32_bf16(a2h.v, b1h, c2, 0, 0, 0);
            c2 = __builtin_amdgcn_mfma_f32_16x16x32_bf16(a2l.v, b1h, c2, 0, 0, 0);
            c2 = __builtin_amdgcn_mfma_f32_16x16x32_bf16(a2h.v, b1l, c2, 0, 0, 0);
            // lane holds eh_pre[edge=q*4+r][h=nb2*16+lo16]
#pragma unroll
            for (int r = 0; r < 4; r++) {
                float v = fmaxf(c2[r] + be1v[nb2], 0.f);
                int idx = (nb2 >> 1) * 512 + ((nb2 & 1) * 2 + (lo16 >> 3)) * 128
                        + (q * 4 + r) * 8 + (lo16 & 7);
                unsigned short hh = f2bf(v);
                ehTH[idx] = hh;
                ehTL[idx] = f2bf(v - bf2f(hh));
            }
        }
        // same-wave LDS RAW: compiler inserts lgkmcnt wait
        bf16x8 b3k0h = *(const bf16x8*)&ehTH[L * 8];
        bf16x8 b3k1h = *(const bf16x8*)&ehTH[512 + L * 8];
        bf16x8 b3k0l = *(const bf16x8*)&ehTL[L * 8];
        bf16x8 b3k1l = *(const bf16x8*)&ehTL[512 + L * 8];

        // msg init: be2 term via mfma(be2^T, x^T) -- C layout matches msg
        BF8 xT;
#pragma unroll
        for (int j = 0; j < 8; j++)
            xT.us[j] = (q < 2) ? f2bf(xr[qc * 8 + j]) : (unsigned short)0;
        f32x4 msg = {0.f, 0.f, 0.f, 0.f};
        msg = __builtin_amdgcn_mfma_f32_16x16x32_bf16(be2T.v, xT.v, msg, 0, 0, 0);

        // stage 3: per M-block (i=mb): C = We2^T @ eh^T (hi+lo B), msg += x[mb]*C
#pragma unroll 4
        for (int mb = 0; mb < 16; mb++) {
            bf16x8 a3a = *(const bf16x8*)&A3sw[((mb * 2 + 0) * 64 + L) * 8];
            bf16x8 a3b = *(const bf16x8*)&A3sw[((mb * 2 + 1) * 64 + L) * 8];
            f32x4 acc = {0.f, 0.f, 0.f, 0.f};
            acc = __builtin_amdgcn_mfma_f32_16x16x32_bf16(a3a, b3k0h, acc, 0, 0, 0);
            acc = __builtin_amdgcn_mfma_f32_16x16x32_bf16(a3b, b3k1h, acc, 0, 0, 0);
            acc = __builtin_amdgcn_mfma_f32_16x16x32_bf16(a3a, b3k0l, acc, 0, 0, 0);
            acc = __builtin_amdgcn_mfma_f32_16x16x32_bf16(a3b, b3k1l, acc, 0, 0, 0);
            float xm = xr[mb];
            msg[0] += xm * acc[0];
            msg[1] += xm * acc[1];
            msg[2] += xm * acc[2];
            msg[3] += xm * acc[3];
        }

        float* np = neigh + (size_t)de * 16 + q * 4;
#pragma unroll
        for (int r = 0; r < 4; r++) atomicAdd(np + r, msg[r]);
    }
}

// ---------------- self path: y = h_self @ W, BN stats ----------------
__global__ __launch_bounds__(256) void self_stats_kernel(
    const float* __restrict__ h_self, const float* __restrict__ W,
    float* __restrict__ y, float* __restrict__ bnacc)
{
    int n = blockIdx.x * 256 + threadIdx.x;
    bool act = (n < NN);
    float hv[16], yv[16];
    if (act) {
        const float4* h4 = (const float4*)(h_self + (size_t)n * 16);
#pragma unroll
        for (int k = 0; k < 4; k++) {
            float4 a = h4[k];
            hv[4*k+0] = a.x; hv[4*k+1] = a.y; hv[4*k+2] = a.z; hv[4*k+3] = a.w;
        }
    } else {
#pragma unroll
        for (int i = 0; i < 16; i++) hv[i] = 0.f;
    }
#pragma unroll
    for (int o = 0; o < 16; o++) {
        float a = 0.f;
#pragma unroll
        for (int i = 0; i < 16; i++) a += hv[i] * W[i*16 + o];
        yv[o] = a;
    }
    if (act) {
        float4* y4 = (float4*)(y + (size_t)n * 16);
#pragma unroll
        for (int k = 0; k < 4; k++)
            y4[k] = make_float4(yv[4*k+0], yv[4*k+1], yv[4*k+2], yv[4*k+3]);
    }
    int lane = threadIdx.x & 63;
#pragma unroll
    for (int o = 0; o < 16; o++) {
        float a = act ? yv[o] : 0.f;
        float b = act ? yv[o]*yv[o] : 0.f;
#pragma unroll
        for (int off = 32; off > 0; off >>= 1) {
            a += __shfl_down(a, off);
            b += __shfl_down(b, off);
        }
        if (lane == 0) {
            atomicAdd(&bnacc[o], a);
            atomicAdd(&bnacc[16 + o], b);
        }
    }
}

// ---- finalize: BN + tanh + add + relu + L2-normalize ----
__global__ __launch_bounds__(256) void final_kernel(
    const float* __restrict__ y, const float* __restrict__ neigh,
    const float* __restrict__ bnacc, const float* __restrict__ gamma,
    const float* __restrict__ beta, float* __restrict__ out)
{
    int n = blockIdx.x * 256 + threadIdx.x;
    if (n >= NN) return;
    float z[16];
    float ss = 0.f;
    const float inv_n = 1.f / (float)NN;
#pragma unroll
    for (int o = 0; o < 16; o++) {
        float mu  = bnacc[o] * inv_n;
        float var = bnacc[16 + o] * inv_n - mu * mu;
        float inv = rsqrtf(var + BN_EPS);
        float yv  = (y[(size_t)n*16 + o] - mu) * inv * gamma[o] + beta[o];
        float tt  = tanhf(yv);
        float zz  = fmaxf(tt + neigh[(size_t)n*16 + o], 0.f);
        z[o] = zz;
        ss += zz * zz;
    }
    float nrm = sqrtf(ss);
    if (nrm == 0.f) nrm = 1.f;
    float r = 1.f / nrm;
#pragma unroll
    for (int o = 0; o < 16; o++) out[(size_t)n*16 + o] = z[o] * r;
}

extern "C" void kernel_launch(void* const* d_in, const int* in_sizes, int n_in,
                              void* d_out, int out_size, void* d_ws, size_t ws_size,
                              hipStream_t stream) {
    const float* h_neigh = (const float*)d_in[0];
    const float* h_self  = (const float*)d_in[1];
    const float* efeat   = (const float*)d_in[2];
    const int*   src     = (const int*)d_in[3];
    const int*   dst     = (const int*)d_in[4];
    const float* W_self  = (const float*)d_in[5];
    const float* gamma   = (const float*)d_in[6];
    const float* beta    = (const float*)d_in[7];
    const float* We1     = (const float*)d_in[8];
    const float* be1     = (const float*)d_in[9];
    const float* We2     = (const float*)d_in[10];
    const float* be2     = (const float*)d_in[11];
    float* out = (float*)d_out;

    char* ws = (char*)d_ws;
    float* neigh = (float*)ws;
    float* bnacc = (float*)(ws + BNACC_OFF);
    float* y     = (float*)(ws + Y_OFF);

    // zero neigh + BN accumulators (ws poisoned 0xAA each call)
    hipMemsetAsync(d_ws, 0, Y_OFF, stream);

    // grid-stride over NE/64 = 5000 wave-tile groups
    edge_kernel<<<1250, 256, 0, stream>>>(
        h_neigh, efeat, src, dst, We1, be1, We2, be2, neigh);
    self_stats_kernel<<<(NN + 255)/256, 256, 0, stream>>>(h_self, W_self, y, bnacc);
    final_kernel<<<(NN + 255)/256, 256, 0, stream>>>(y, neigh, bnacc, gamma, beta, out);
}

// Round 6
// 182.973 us; speedup vs baseline: 3.0188x; 1.4445x over previous
//
#include <hip/hip_runtime.h>
#include <hip/hip_bf16.h>
#include <math.h>

#define NN 20000
#define NE 320000
#define BN_EPS 1e-5f

// ws layout
#define NEIGH_BYTES (NN * 16 * 4)
#define BNACC_OFF   NEIGH_BYTES
#define Y_OFF       (NEIGH_BYTES + 128)

typedef __bf16 bf16x8 __attribute__((ext_vector_type(8)));
typedef float  f32x4  __attribute__((ext_vector_type(4)));

union BF8 { bf16x8 v; unsigned short us[8]; unsigned int ui[4]; };

__device__ __forceinline__ unsigned short f2bf(float f) {
    unsigned int u = __builtin_bit_cast(unsigned int, f);
    u += 0x7FFFu + ((u >> 16) & 1u);   // RNE
    return (unsigned short)(u >> 16);
}
__device__ __forceinline__ float bf2f(unsigned short s) {
    unsigned int u = ((unsigned int)s) << 16;
    return __builtin_bit_cast(float, u);
}
__device__ __forceinline__ unsigned int pack2bf(float a, float b) {
    return (unsigned int)f2bf(a) | ((unsigned int)f2bf(b) << 16);
}

// ============================ edge path (+fused self stats) ============================
// Stage 2 (transposed): ehT = relu(We1^T @ ef^T + be1) -- We1^T A-frags in REGISTERS
//   (hi/lo split), bias folded into K-padding slot k=16 (A=be1, B=1.0).
// C-layout -> stage-3 B-frag via ds_bpermute. Mapping (verified by derivation):
//   target lane (q,e), frag kb, element j: h = kb*32+q*8+j ->
//     chunk c = kb*2 + (q>>1)  [TARGET-side property!]
//     source lane = ((q&1)*2 + (j>>2))*16 + e, dword d = (j>>1)&1.
//   Since c depends on the target's q>>1 but bpermute's source operand is
//   source-lane-computed, we pull BOTH chunk candidates and cndmask-select.
// Stage 3: per mb(=i): C = We2^T @ ehT (A-frags from 32KB LDS), x-reduction fused fp32.
// Blocks 945..1023 additionally compute y = h_self@W + block-reduced BN stats.
__global__ __launch_bounds__(256, 4) void edge_kernel(
    const float* __restrict__ h_neigh, const float* __restrict__ efeat,
    const int* __restrict__ src, const int* __restrict__ dst,
    const float* __restrict__ We1, const float* __restrict__ be1,
    const float* __restrict__ We2, const float* __restrict__ be2,
    float* __restrict__ neigh,
    const float* __restrict__ h_self, const float* __restrict__ Wsf,
    float* __restrict__ y, float* __restrict__ bnacc)
{
    // A-frag-swizzled We2^T: [mb][kb][lane][j]  32 KB
    __shared__ __align__(16) unsigned short A3sw[16 * 2 * 64 * 8];
    __shared__ float red[4][32];   // self-path block reduction

    const int t = threadIdx.x;

    // ---- init A3sw from We2 (coalesced float4 reads, swizzled b16 writes)
    {
        const float4* W2v = (const float4*)We2;
#pragma unroll
        for (int it = 0; it < 16; it++) {
            int c4 = t + 256 * it;          // 0..4095 float4 chunks
            float4 w = W2v[c4];
            int f = c4 * 4;
            int h = f >> 8, c = f & 255;
            int mb = c >> 4, kb = h >> 5, hh = h & 31, co = c & 15;
            int base = ((mb * 2 + kb) * 64 + (hh >> 3) * 16) * 8 + (hh & 7);
            A3sw[base + (co + 0) * 8] = f2bf(w.x);
            A3sw[base + (co + 1) * 8] = f2bf(w.y);
            A3sw[base + (co + 2) * 8] = f2bf(w.z);
            A3sw[base + (co + 3) * 8] = f2bf(w.w);
        }
    }
    __syncthreads();

    const int L = t & 63, wv = t >> 6;
    const int lo16 = L & 15, q = L >> 4;
    const int qc = q & 1;
    const bool qlow = (q < 2);
    const bool qhi1 = ((q >> 1) != 0);   // target-side chunk select

    // ---- We1^T A-frags (hi/lo) in registers, bias in slot k=16
    BF8 w1h[4], w1l[4];
#pragma unroll
    for (int c = 0; c < 4; c++) {
#pragma unroll
        for (int j = 0; j < 8; j++) {
            float w;
            if (q < 2)                 w = We1[(q * 8 + j) * 64 + c * 16 + lo16];
            else if (q == 2 && j == 0) w = be1[c * 16 + lo16];
            else                       w = 0.f;
            unsigned short h = f2bf(w);
            w1h[c].us[j] = h;
            w1l[c].us[j] = f2bf(w - bf2f(h));
        }
    }

    // A-frag of be2^T
    BF8 be2T;
#pragma unroll
    for (int j = 0; j < 8; j++) {
        float bv = be2[(qc * 8 + j) * 16 + lo16];
        be2T.us[j] = qlow ? f2bf(bv) : (unsigned short)0;
    }

    // bpermute source-lane byte addresses (loop-invariant):
    // src lane = ((q&1)*2 + (tt>>1))*16 + e
    const int addrA = (((q & 1) * 2 + 0) * 16 + lo16) * 4;   // tt>>1 == 0
    const int addrB = (((q & 1) * 2 + 1) * 16 + lo16) * 4;   // tt>>1 == 1

    for (int bt = blockIdx.x; bt < NE / 64; bt += gridDim.x) {
        int e = bt * 64 + wv * 16 + lo16;
        int se = src[e];
        int de = dst[e];

        float xr[16];
        {
            const float4* xp = (const float4*)(h_neigh + (size_t)se * 16);
#pragma unroll
            for (int k4 = 0; k4 < 4; k4++) {
                float4 a = xp[k4];
                xr[k4*4+0] = a.x; xr[k4*4+1] = a.y; xr[k4*4+2] = a.z; xr[k4*4+3] = a.w;
            }
        }

        // B-frag of ef^T (hi/lo), bias partner 1.0 at (q==2, j==0)
        BF8 a2h, a2l;
        {
            const float4* ep = (const float4*)(efeat + (size_t)e * 16 + qc * 8);
            float4 e0 = ep[0], e1 = ep[1];
            float ev[8] = {e0.x, e0.y, e0.z, e0.w, e1.x, e1.y, e1.z, e1.w};
#pragma unroll
            for (int j = 0; j < 8; j++) {
                if (qlow) {
                    unsigned short h = f2bf(ev[j]);
                    a2h.us[j] = h;
                    a2l.us[j] = f2bf(ev[j] - bf2f(h));
                } else {
                    a2h.us[j] = (q == 2 && j == 0) ? (unsigned short)0x3F80 : (unsigned short)0;
                    a2l.us[j] = 0;
                }
            }
        }

        // stage 2T: ehT chunk c holds rows h = c*16 + q*4 + r, col = edge lo16
        float vch[4][4];
#pragma unroll
        for (int c = 0; c < 4; c++) {
            f32x4 c2 = {0.f, 0.f, 0.f, 0.f};
            c2 = __builtin_amdgcn_mfma_f32_16x16x32_bf16(w1h[c].v, a2h.v, c2, 0, 0, 0);
            c2 = __builtin_amdgcn_mfma_f32_16x16x32_bf16(w1l[c].v, a2h.v, c2, 0, 0, 0);
            c2 = __builtin_amdgcn_mfma_f32_16x16x32_bf16(w1h[c].v, a2l.v, c2, 0, 0, 0);
#pragma unroll
            for (int r = 0; r < 4; r++) vch[c][r] = fmaxf(c2[r], 0.f);
        }

        // pack hi/lo dword pairs: dw[c][d] = (bf16(v[2d]), bf16(v[2d+1]))
        unsigned int dwH[4][2], dwL[4][2];
#pragma unroll
        for (int c = 0; c < 4; c++) {
#pragma unroll
            for (int d = 0; d < 2; d++) {
                float va = vch[c][2*d], vb = vch[c][2*d+1];
                unsigned short ha = f2bf(va), hb = f2bf(vb);
                dwH[c][d] = (unsigned int)ha | ((unsigned int)hb << 16);
                dwL[c][d] = pack2bf(va - bf2f(ha), vb - bf2f(hb));
            }
        }

        // pulls -> stage-3 B-frags: pull BOTH chunk candidates, select by q>>1
        BF8 b3h[2], b3l[2];
#pragma unroll
        for (int kb = 0; kb < 2; kb++) {
#pragma unroll
            for (int tt = 0; tt < 4; tt++) {
                int d = tt & 1;
                int addr = (tt >> 1) ? addrB : addrA;
                int h0 = __builtin_amdgcn_ds_bpermute(addr, (int)dwH[kb*2+0][d]);
                int h1 = __builtin_amdgcn_ds_bpermute(addr, (int)dwH[kb*2+1][d]);
                int l0 = __builtin_amdgcn_ds_bpermute(addr, (int)dwL[kb*2+0][d]);
                int l1 = __builtin_amdgcn_ds_bpermute(addr, (int)dwL[kb*2+1][d]);
                b3h[kb].ui[tt] = (unsigned int)(qhi1 ? h1 : h0);
                b3l[kb].ui[tt] = (unsigned int)(qhi1 ? l1 : l0);
            }
        }

        // be2 term: msg = be2^T @ x^T  (C layout matches msg)
        BF8 xT;
#pragma unroll
        for (int j = 0; j < 8; j++)
            xT.us[j] = qlow ? f2bf(xr[qc * 8 + j]) : (unsigned short)0;
        f32x4 msg = {0.f, 0.f, 0.f, 0.f};
        msg = __builtin_amdgcn_mfma_f32_16x16x32_bf16(be2T.v, xT.v, msg, 0, 0, 0);

        // stage 3: per mb(=i): C = We2^T @ ehT, msg += x[i]*C
#pragma unroll 4
        for (int mb = 0; mb < 16; mb++) {
            bf16x8 a3a = *(const bf16x8*)&A3sw[((mb * 2 + 0) * 64 + L) * 8];
            bf16x8 a3b = *(const bf16x8*)&A3sw[((mb * 2 + 1) * 64 + L) * 8];
            f32x4 acc = {0.f, 0.f, 0.f, 0.f};
            acc = __builtin_amdgcn_mfma_f32_16x16x32_bf16(a3a, b3h[0].v, acc, 0, 0, 0);
            acc = __builtin_amdgcn_mfma_f32_16x16x32_bf16(a3b, b3h[1].v, acc, 0, 0, 0);
            acc = __builtin_amdgcn_mfma_f32_16x16x32_bf16(a3a, b3l[0].v, acc, 0, 0, 0);
            acc = __builtin_amdgcn_mfma_f32_16x16x32_bf16(a3b, b3l[1].v, acc, 0, 0, 0);
            float xm = xr[mb];
            msg[0] += xm * acc[0];
            msg[1] += xm * acc[1];
            msg[2] += xm * acc[2];
            msg[3] += xm * acc[3];
        }

        float* np = neigh + (size_t)de * 16 + q * 4;
#pragma unroll
        for (int r = 0; r < 4; r++) atomicAdd(np + r, msg[r]);
    }

    // ---------------- fused self path (blocks 945..1023) ----------------
    int sb = (int)blockIdx.x - 945;
    if (sb >= 0 && sb < 79) {
        int n = sb * 256 + t;
        bool act = (n < NN);
        float hv[16], yv[16];
        if (act) {
            const float4* h4 = (const float4*)(h_self + (size_t)n * 16);
#pragma unroll
            for (int k = 0; k < 4; k++) {
                float4 a = h4[k];
                hv[4*k+0] = a.x; hv[4*k+1] = a.y; hv[4*k+2] = a.z; hv[4*k+3] = a.w;
            }
        } else {
#pragma unroll
            for (int i = 0; i < 16; i++) hv[i] = 0.f;
        }
#pragma unroll
        for (int o = 0; o < 16; o++) {
            float a = 0.f;
#pragma unroll
            for (int i = 0; i < 16; i++) a += hv[i] * Wsf[i*16 + o];
            yv[o] = a;
        }
        if (act) {
            float4* y4 = (float4*)(y + (size_t)n * 16);
#pragma unroll
            for (int k = 0; k < 4; k++)
                y4[k] = make_float4(yv[4*k+0], yv[4*k+1], yv[4*k+2], yv[4*k+3]);
        }
        int lane = t & 63;
#pragma unroll
        for (int o = 0; o < 16; o++) {
            float a = act ? yv[o] : 0.f;
            float b = act ? yv[o]*yv[o] : 0.f;
#pragma unroll
            for (int off = 32; off > 0; off >>= 1) {
                a += __shfl_down(a, off);
                b += __shfl_down(b, off);
            }
            if (lane == 0) { red[wv][o] = a; red[wv][16 + o] = b; }
        }
        __syncthreads();
        if (t < 32) {
            float s = red[0][t] + red[1][t] + red[2][t] + red[3][t];
            atomicAdd(&bnacc[t], s);
        }
    }
}

// ---- finalize: BN + tanh + add + relu + L2-normalize ----
__global__ __launch_bounds__(256) void final_kernel(
    const float* __restrict__ y, const float* __restrict__ neigh,
    const float* __restrict__ bnacc, const float* __restrict__ gamma,
    const float* __restrict__ beta, float* __restrict__ out)
{
    int n = blockIdx.x * 256 + threadIdx.x;
    if (n >= NN) return;
    float z[16];
    float ss = 0.f;
    const float inv_n = 1.f / (float)NN;
#pragma unroll
    for (int o = 0; o < 16; o++) {
        float mu  = bnacc[o] * inv_n;
        float var = bnacc[16 + o] * inv_n - mu * mu;
        float inv = rsqrtf(var + BN_EPS);
        float yv  = (y[(size_t)n*16 + o] - mu) * inv * gamma[o] + beta[o];
        float tt  = tanhf(yv);
        float zz  = fmaxf(tt + neigh[(size_t)n*16 + o], 0.f);
        z[o] = zz;
        ss += zz * zz;
    }
    float nrm = sqrtf(ss);
    if (nrm == 0.f) nrm = 1.f;
    float r = 1.f / nrm;
#pragma unroll
    for (int o = 0; o < 16; o++) out[(size_t)n*16 + o] = z[o] * r;
}

extern "C" void kernel_launch(void* const* d_in, const int* in_sizes, int n_in,
                              void* d_out, int out_size, void* d_ws, size_t ws_size,
                              hipStream_t stream) {
    const float* h_neigh = (const float*)d_in[0];
    const float* h_self  = (const float*)d_in[1];
    const float* efeat   = (const float*)d_in[2];
    const int*   src     = (const int*)d_in[3];
    const int*   dst     = (const int*)d_in[4];
    const float* W_self  = (const float*)d_in[5];
    const float* gamma   = (const float*)d_in[6];
    const float* beta    = (const float*)d_in[7];
    const float* We1     = (const float*)d_in[8];
    const float* be1     = (const float*)d_in[9];
    const float* We2     = (const float*)d_in[10];
    const float* be2     = (const float*)d_in[11];
    float* out = (float*)d_out;

    char* ws = (char*)d_ws;
    float* neigh = (float*)ws;
    float* bnacc = (float*)(ws + BNACC_OFF);
    float* y     = (float*)(ws + Y_OFF);

    // zero neigh + BN accumulators (ws poisoned 0xAA each call)
    hipMemsetAsync(d_ws, 0, Y_OFF, stream);

    // 1024 blocks = 4/CU resident; grid-stride over 5000 wave-tile groups;
    // blocks 945..1023 also do the self path.
    edge_kernel<<<1024, 256, 0, stream>>>(
        h_neigh, efeat, src, dst, We1, be1, We2, be2, neigh,
        h_self, W_self, y, bnacc);
    final_kernel<<<(NN + 255)/256, 256, 0, stream>>>(y, neigh, bnacc, gamma, beta, out);
}